// Round 10
// baseline (204.259 us; speedup 1.0000x reference)
//
#include <hip/hip_runtime.h>

// GCN2: h1 = relu(gcn(x,W1,b1)); h2 = relu(gcn(h1,W2,b2)); out = h2@Wlin+blin
// dinv[s] folded into fp16 h'. CSR via bucket sort (dst>>6), ss as ushort.
// Dense GEMMs on v_mfma_f32_16x16x32_f16. Aggregation: features split into
// column-quarter buffers (3.2MB each < 4MB XCD L2); phases run quarter-major
// so each XCD's L2 holds the whole quarter -> gathers are L2 hits. 64B rows
// give 16 edges per h8 load instruction (64 lanes x 16B).

constexpr int FDIM = 128;
constexpr int CDIM = 40;
constexpr int NPB  = 64;    // nodes per bucket
constexpr int MAXNB = 1024; // max buckets
constexpr int CH   = 4096;  // edges per partition block

typedef _Float16 h8  __attribute__((ext_vector_type(8)));
typedef _Float16 h4  __attribute__((ext_vector_type(4)));
typedef float    f4  __attribute__((ext_vector_type(4)));
typedef unsigned short u16;

static inline size_t AL512(size_t x) { return (x + 511) & ~size_t(511); }

// --- weight prep + zero bcnt ---
__global__ __launch_bounds__(256) void k_prep(const float* __restrict__ W1,
        const float* __restrict__ W2, _Float16* __restrict__ W1t,
        _Float16* __restrict__ W2t, int* __restrict__ bcnt, int nb) {
    int i = blockIdx.x * 256 + threadIdx.x;
    if (i < nb) bcnt[i] = 0;
    if (i < 128 * 128) {
        int c = i >> 7, k = i & 127;
        W1t[c * 128 + k] = (_Float16)W1[k * 128 + c];
    }
    int j = i - 128 * 128;
    if (j >= 0 && j < 48 * 128) {
        int c = j >> 7, k = j & 127;
        W2t[c * 128 + k] = (c < CDIM) ? (_Float16)W2[k * CDIM + c] : (_Float16)0.f;
    }
}

// --- bucket histogram of dst>>6 ---
__global__ __launch_bounds__(256) void k_bhist(const int* __restrict__ dst,
        int* __restrict__ bcnt, int E, int nb) {
    __shared__ int h[MAXNB];
    for (int i = threadIdx.x; i < nb; i += 256) h[i] = 0;
    __syncthreads();
    for (int i = blockIdx.x * 256 + threadIdx.x; i < E; i += gridDim.x * 256)
        atomicAdd(&h[dst[i] >> 6], 1);
    __syncthreads();
    for (int i = threadIdx.x; i < nb; i += 256) {
        int c = h[i];
        if (c) atomicAdd(&bcnt[i], c);
    }
}

// --- single-block scan over nb bucket counts -> bbase, bcur ---
__global__ __launch_bounds__(1024) void k_bscan(const int* __restrict__ bcnt,
        int* __restrict__ bbase, int* __restrict__ bcur, int nb, int E) {
    __shared__ int tmp[1024];
    int t = threadIdx.x;
    int v = (t < nb) ? bcnt[t] : 0;
    tmp[t] = v;
    __syncthreads();
    for (int o = 1; o < 1024; o <<= 1) {
        int u = (t >= o) ? tmp[t - o] : 0;
        __syncthreads();
        tmp[t] += u;
        __syncthreads();
    }
    if (t < nb) { int b = tmp[t] - v; bbase[t] = b; bcur[t] = b; }
    if (t == 0) bbase[nb] = E;
}

// --- chunked counting sort into bucket runs, packed (src<<6)|(dst&63) ---
__global__ __launch_bounds__(256) void k_partition(const int* __restrict__ src,
        const int* __restrict__ dst, int* __restrict__ bcur,
        unsigned* __restrict__ eb, int E, int nb) {
    __shared__ int hcnt[MAXNB];
    __shared__ int gb[MAXNB];
    int e0 = blockIdx.x * CH;
    int cnt = min(CH, E - e0);
    for (int i = threadIdx.x; i < nb; i += 256) hcnt[i] = 0;
    __syncthreads();
    for (int i = threadIdx.x; i < cnt; i += 256)
        atomicAdd(&hcnt[dst[e0 + i] >> 6], 1);
    __syncthreads();
    for (int i = threadIdx.x; i < nb; i += 256) {
        int c = hcnt[i];
        if (c) gb[i] = atomicAdd(&bcur[i], c);
        hcnt[i] = 0;  // reuse as local cursor
    }
    __syncthreads();
    for (int i = threadIdx.x; i < cnt; i += 256) {
        int d = dst[e0 + i], b = d >> 6;
        int p = atomicAdd(&hcnt[b], 1);
        eb[gb[b] + p] = ((unsigned)src[e0 + i] << 6) | (unsigned)(d & 63);
    }
}

// --- per-bucket counting sort -> per-node CSR (offs, ss u16) + dinv ---
__global__ __launch_bounds__(256) void k_bucket_csr(const unsigned* __restrict__ eb,
        const int* __restrict__ bbase, int* __restrict__ offs,
        float* __restrict__ dinv, u16* __restrict__ ss, int n) {
    __shared__ int cnt[NPB];
    __shared__ int cur[NPB];
    int b = blockIdx.x;
    int beg = bbase[b], end = bbase[b + 1];
    if (threadIdx.x < NPB) cnt[threadIdx.x] = 0;
    __syncthreads();
    for (int i = beg + threadIdx.x; i < end; i += 256)
        atomicAdd(&cnt[eb[i] & 63], 1);
    __syncthreads();
    if (threadIdx.x < NPB) {  // wave 0: 64-lane inclusive shfl scan
        int v = cnt[threadIdx.x];
        int s = v;
#pragma unroll
        for (int o = 1; o < NPB; o <<= 1) {
            int u = __shfl_up(s, o, 64);
            if (threadIdx.x >= (unsigned)o) s += u;
        }
        int e0 = beg + s - v;
        cur[threadIdx.x] = e0;
        int node = b * NPB + threadIdx.x;
        if (node < n) {
            offs[node] = e0;
            dinv[node] = rsqrtf((float)v + 1.0f);  // +1 self loop
        }
    }
    __syncthreads();
    for (int i = beg + threadIdx.x; i < end; i += 256) {
        unsigned p = eb[i];
        int pos = atomicAdd(&cur[p & 63], 1);
        ss[pos] = (u16)(p >> 6);
    }
}

// Hp quarters: hpq[q][r][0..31] = fp16((X[r]@W1)[q*32..] * dinv[r])
__global__ __launch_bounds__(256) void k_gemm1(const float* __restrict__ X,
        const _Float16* __restrict__ W1t, const float* __restrict__ dinv,
        _Float16* __restrict__ Hp, int n) {
    __shared__ _Float16 xh[64][136];   // +8 pad: 2-way LDS conflict (free)
    __shared__ _Float16 wt[128][136];
    int t = threadIdx.x;
    int r0 = blockIdx.x * 64;
    size_t qs = (size_t)n * 32;
    for (int i = t; i < 64 * 32; i += 256) {
        int r = i >> 5, c4 = (i & 31) * 4;
        int gr = r0 + r;
        float4 v = make_float4(0.f, 0.f, 0.f, 0.f);
        if (gr < n) v = *(const float4*)&X[(size_t)gr * 128 + c4];
        h4 hv; hv[0] = (_Float16)v.x; hv[1] = (_Float16)v.y;
               hv[2] = (_Float16)v.z; hv[3] = (_Float16)v.w;
        *(h4*)&xh[r][c4] = hv;
    }
    for (int i = t; i < 128 * 16; i += 256) {
        int r = i >> 4, c8 = (i & 15) * 8;
        *(uint4*)&wt[r][c8] = *(const uint4*)&W1t[r * 128 + c8];
    }
    __syncthreads();
    int wid = t >> 6, lane = t & 63;
    int fr = lane & 15, fg = lane >> 4;
    f4 acc[8];
#pragma unroll
    for (int ct = 0; ct < 8; ++ct) acc[ct] = (f4){0.f, 0.f, 0.f, 0.f};
#pragma unroll
    for (int ks = 0; ks < 4; ++ks) {
        h8 a = *(const h8*)&xh[wid * 16 + fr][ks * 32 + fg * 8];
#pragma unroll
        for (int ct = 0; ct < 8; ++ct) {
            h8 b = *(const h8*)&wt[ct * 16 + fr][ks * 32 + fg * 8];
            acc[ct] = __builtin_amdgcn_mfma_f32_16x16x32_f16(a, b, acc[ct], 0, 0, 0);
        }
    }
    int rbase = r0 + wid * 16 + fg * 4;  // C/D: row=(lane>>4)*4+reg, col=lane&15
    float dv[4];
#pragma unroll
    for (int rg = 0; rg < 4; ++rg) dv[rg] = (rbase + rg < n) ? dinv[rbase + rg] : 0.f;
#pragma unroll
    for (int ct = 0; ct < 8; ++ct) {
        int q = ct >> 1, cq = (ct & 1) * 16 + fr;
#pragma unroll
        for (int rg = 0; rg < 4; ++rg) {
            int gr = rbase + rg;
            if (gr < n) Hp[q * qs + (size_t)gr * 32 + cq] = (_Float16)(acc[ct][rg] * dv[rg]);
        }
    }
}

// h1 quarters: one wave per (node, quarter); 64B rows -> 16 edges/load.
// Quarter-major dispatch keeps each 3.2MB quarter XCD-L2-resident.
__global__ __launch_bounds__(256) void k_agg128(const u16* __restrict__ ss,
        const int* __restrict__ offs, const _Float16* __restrict__ hp,
        const float* __restrict__ b1, const float* __restrict__ dinv,
        _Float16* __restrict__ h1, int n, int E, int nbq) {
    int b = blockIdx.x;
    int q = b / nbq;
    int w = (b - q * nbq) * 4 + (threadIdx.x >> 6);
    if (w >= n) return;
    int lane = threadIdx.x & 63;
    int g = lane >> 2, c = lane & 3;
    size_t qs = (size_t)n * 32;
    const h8* base = (const h8*)(hp + q * qs);  // 4 h8 per 32-col row
    int beg = offs[w];
    int end = (w == n - 1) ? E : offs[w + 1];
    float acc[8];
    if (g == 0) {
        h8 sv = base[(size_t)w * 4 + c];  // self loop
#pragma unroll
        for (int i = 0; i < 8; ++i) acc[i] = (float)sv[i];
    } else {
#pragma unroll
        for (int i = 0; i < 8; ++i) acc[i] = 0.f;
    }
    int j = beg;
    for (; j + 16 < end; j += 32) {  // 2 rounds in flight
        int i0 = j + g, i1 = j + 16 + g;
        int s0 = ss[i0];
        bool p1 = i1 < end;
        int s1 = p1 ? (int)ss[i1] : s0;
        h8 v0 = base[(size_t)s0 * 4 + c];
        h8 v1 = base[(size_t)s1 * 4 + c];
#pragma unroll
        for (int i = 0; i < 8; ++i) {
            acc[i] += (float)v0[i];
            if (p1) acc[i] += (float)v1[i];
        }
    }
    for (; j < end; j += 16) {
        int idx = j + g;
        if (idx < end) {
            int s = ss[idx];
            h8 v = base[(size_t)s * 4 + c];
#pragma unroll
            for (int i = 0; i < 8; ++i) acc[i] += (float)v[i];
        }
    }
#pragma unroll
    for (int i = 0; i < 8; ++i) {  // fold 16 group-partials (g bits 2..5)
        acc[i] += __shfl_xor(acc[i], 4);
        acc[i] += __shfl_xor(acc[i], 8);
        acc[i] += __shfl_xor(acc[i], 16);
        acc[i] += __shfl_xor(acc[i], 32);
    }
    if (lane < 4) {  // lane=c holds quarter cols 8c..8c+7
        float dvv = dinv[w];
        int col0 = q * 32 + lane * 8;
        const float4 bb0 = *(const float4*)&b1[col0];
        const float4 bb1 = *(const float4*)&b1[col0 + 4];
        h8 o;
        o[0] = (_Float16)fmaxf(fmaf(dvv, acc[0], bb0.x), 0.f);
        o[1] = (_Float16)fmaxf(fmaf(dvv, acc[1], bb0.y), 0.f);
        o[2] = (_Float16)fmaxf(fmaf(dvv, acc[2], bb0.z), 0.f);
        o[3] = (_Float16)fmaxf(fmaf(dvv, acc[3], bb0.w), 0.f);
        o[4] = (_Float16)fmaxf(fmaf(dvv, acc[4], bb1.x), 0.f);
        o[5] = (_Float16)fmaxf(fmaf(dvv, acc[5], bb1.y), 0.f);
        o[6] = (_Float16)fmaxf(fmaf(dvv, acc[6], bb1.z), 0.f);
        o[7] = (_Float16)fmaxf(fmaf(dvv, acc[7], bb1.w), 0.f);
        ((h8*)(h1 + q * qs))[(size_t)w * 4 + lane] = o;
    }
}

// Hp2 split: hp2a[n][32] (cols 0-31), hp2b[n][8] (cols 32-39). ct3 dropped.
__global__ __launch_bounds__(256) void k_gemm2(const _Float16* __restrict__ H1,
        const _Float16* __restrict__ W2t, const float* __restrict__ dinv,
        _Float16* __restrict__ Hp2a, _Float16* __restrict__ Hp2b, int n) {
    __shared__ _Float16 xh[64][136];
    __shared__ _Float16 wt[48][136];
    int t = threadIdx.x;
    int r0 = blockIdx.x * 64;
    size_t qs = (size_t)n * 32;
    for (int i = t; i < 64 * 16; i += 256) {
        int r = i >> 4, c8 = i & 15;
        int gr = r0 + r;
        uint4 v = make_uint4(0u, 0u, 0u, 0u);
        if (gr < n) {
            int q = c8 >> 2, within = (c8 & 3) * 8;
            v = *(const uint4*)&H1[q * qs + (size_t)gr * 32 + within];
        }
        *(uint4*)&xh[r][c8 * 8] = v;
    }
    for (int i = t; i < 48 * 16; i += 256) {
        int r = i >> 4, c8 = (i & 15) * 8;
        *(uint4*)&wt[r][c8] = *(const uint4*)&W2t[r * 128 + c8];
    }
    __syncthreads();
    int wid = t >> 6, lane = t & 63;
    int fr = lane & 15, fg = lane >> 4;
    f4 acc[3];
#pragma unroll
    for (int ct = 0; ct < 3; ++ct) acc[ct] = (f4){0.f, 0.f, 0.f, 0.f};
#pragma unroll
    for (int ks = 0; ks < 4; ++ks) {
        h8 a = *(const h8*)&xh[wid * 16 + fr][ks * 32 + fg * 8];
#pragma unroll
        for (int ct = 0; ct < 3; ++ct) {
            h8 b = *(const h8*)&wt[ct * 16 + fr][ks * 32 + fg * 8];
            acc[ct] = __builtin_amdgcn_mfma_f32_16x16x32_f16(a, b, acc[ct], 0, 0, 0);
        }
    }
    int rbase = r0 + wid * 16 + fg * 4;
    float dv[4];
#pragma unroll
    for (int rg = 0; rg < 4; ++rg) dv[rg] = (rbase + rg < n) ? dinv[rbase + rg] : 0.f;
#pragma unroll
    for (int rg = 0; rg < 4; ++rg) {
        int gr = rbase + rg;
        if (gr >= n) continue;
        Hp2a[(size_t)gr * 32 + fr]      = (_Float16)(acc[0][rg] * dv[rg]);
        Hp2a[(size_t)gr * 32 + 16 + fr] = (_Float16)(acc[1][rg] * dv[rg]);
        if (fr < 8) Hp2b[(size_t)gr * 8 + fr] = (_Float16)(acc[2][rg] * dv[rg]);
    }
}

// h2 (fp32, d_out): passA cols 0-31 from hp2a (64B rows, 16 edges/load),
// passB cols 32-39 from hp2b (16B rows, 64 edges/load).
__global__ __launch_bounds__(256) void k_agg40(const u16* __restrict__ ss,
        const int* __restrict__ offs, const _Float16* __restrict__ hpa,
        const _Float16* __restrict__ hpb, const float* __restrict__ b2,
        const float* __restrict__ dinv, float* __restrict__ h2out,
        int n, int E, int nbq) {
    int b = blockIdx.x;
    int q = b / nbq;  // 0 = passA, 1 = passB
    int w = (b - q * nbq) * 4 + (threadIdx.x >> 6);
    if (w >= n) return;
    int lane = threadIdx.x & 63;
    int beg = offs[w];
    int end = (w == n - 1) ? E : offs[w + 1];
    if (q == 0) {
        int g = lane >> 2, c = lane & 3;
        const h8* base = (const h8*)hpa;
        float acc[8];
        if (g == 0) {
            h8 sv = base[(size_t)w * 4 + c];
#pragma unroll
            for (int i = 0; i < 8; ++i) acc[i] = (float)sv[i];
        } else {
#pragma unroll
            for (int i = 0; i < 8; ++i) acc[i] = 0.f;
        }
        int j = beg;
        for (; j + 16 < end; j += 32) {
            int i0 = j + g, i1 = j + 16 + g;
            int s0 = ss[i0];
            bool p1 = i1 < end;
            int s1 = p1 ? (int)ss[i1] : s0;
            h8 v0 = base[(size_t)s0 * 4 + c];
            h8 v1 = base[(size_t)s1 * 4 + c];
#pragma unroll
            for (int i = 0; i < 8; ++i) {
                acc[i] += (float)v0[i];
                if (p1) acc[i] += (float)v1[i];
            }
        }
        for (; j < end; j += 16) {
            int idx = j + g;
            if (idx < end) {
                int s = ss[idx];
                h8 v = base[(size_t)s * 4 + c];
#pragma unroll
                for (int i = 0; i < 8; ++i) acc[i] += (float)v[i];
            }
        }
#pragma unroll
        for (int i = 0; i < 8; ++i) {
            acc[i] += __shfl_xor(acc[i], 4);
            acc[i] += __shfl_xor(acc[i], 8);
            acc[i] += __shfl_xor(acc[i], 16);
            acc[i] += __shfl_xor(acc[i], 32);
        }
        if (lane < 4) {
            float dvv = dinv[w];
            int col0 = lane * 8;
            const float4 bb0 = *(const float4*)&b2[col0];
            const float4 bb1 = *(const float4*)&b2[col0 + 4];
            float4 r0, r1;
            r0.x = fmaxf(fmaf(dvv, acc[0], bb0.x), 0.f);
            r0.y = fmaxf(fmaf(dvv, acc[1], bb0.y), 0.f);
            r0.z = fmaxf(fmaf(dvv, acc[2], bb0.z), 0.f);
            r0.w = fmaxf(fmaf(dvv, acc[3], bb0.w), 0.f);
            r1.x = fmaxf(fmaf(dvv, acc[4], bb1.x), 0.f);
            r1.y = fmaxf(fmaf(dvv, acc[5], bb1.y), 0.f);
            r1.z = fmaxf(fmaf(dvv, acc[6], bb1.z), 0.f);
            r1.w = fmaxf(fmaf(dvv, acc[7], bb1.w), 0.f);
            *(float4*)&h2out[(size_t)w * CDIM + col0] = r0;
            *(float4*)&h2out[(size_t)w * CDIM + col0 + 4] = r1;
        }
    } else {
        const h8* base = (const h8*)hpb;  // 1 h8 per 8-col row
        h8 selfv = base[w];               // wave-uniform broadcast load
        float acc[8];
#pragma unroll
        for (int i = 0; i < 8; ++i) acc[i] = 0.f;
        for (int j = beg; j < end; j += 64) {
            int idx = j + lane;
            if (idx < end) {
                int s = ss[idx];
                h8 v = base[s];
#pragma unroll
                for (int i = 0; i < 8; ++i) acc[i] += (float)v[i];
            }
        }
#pragma unroll
        for (int i = 0; i < 8; ++i) {
            acc[i] += __shfl_xor(acc[i], 1);
            acc[i] += __shfl_xor(acc[i], 2);
            acc[i] += __shfl_xor(acc[i], 4);
            acc[i] += __shfl_xor(acc[i], 8);
            acc[i] += __shfl_xor(acc[i], 16);
            acc[i] += __shfl_xor(acc[i], 32);
        }
        if (lane == 0) {
            float dvv = dinv[w];
            const float4 bb0 = *(const float4*)&b2[32];
            const float4 bb1 = *(const float4*)&b2[36];
            float4 r0, r1;
            r0.x = fmaxf(fmaf(dvv, acc[0] + (float)selfv[0], bb0.x), 0.f);
            r0.y = fmaxf(fmaf(dvv, acc[1] + (float)selfv[1], bb0.y), 0.f);
            r0.z = fmaxf(fmaf(dvv, acc[2] + (float)selfv[2], bb0.z), 0.f);
            r0.w = fmaxf(fmaf(dvv, acc[3] + (float)selfv[3], bb0.w), 0.f);
            r1.x = fmaxf(fmaf(dvv, acc[4] + (float)selfv[4], bb1.x), 0.f);
            r1.y = fmaxf(fmaf(dvv, acc[5] + (float)selfv[5], bb1.y), 0.f);
            r1.z = fmaxf(fmaf(dvv, acc[6] + (float)selfv[6], bb1.z), 0.f);
            r1.w = fmaxf(fmaf(dvv, acc[7] + (float)selfv[7], bb1.w), 0.f);
            *(float4*)&h2out[(size_t)w * CDIM + 32] = r0;
            *(float4*)&h2out[(size_t)w * CDIM + 36] = r1;
        }
    }
}

// lin_out = h2 @ Wlin + blin  (h2 read back from d_out)
__global__ __launch_bounds__(256) void k_final(const float* __restrict__ h2,
        const float* __restrict__ Wlin, const float* __restrict__ blin,
        float* __restrict__ lin_out, int n) {
    __shared__ float wl[CDIM * CDIM];
    __shared__ float hs[32 * CDIM];
    int t = threadIdx.x;
    int r0 = blockIdx.x * 32;
    for (int i = t; i < CDIM * CDIM; i += 256) wl[i] = Wlin[i];
    int lim = n * CDIM - r0 * CDIM;
    for (int i = t; i < 32 * CDIM; i += 256)
        hs[i] = (i < lim) ? h2[(size_t)r0 * CDIM + i] : 0.f;
    __syncthreads();
    for (int i = t; i < 32 * CDIM; i += 256) {
        int r = i / CDIM, c = i % CDIM;
        int gr = r0 + r;
        if (gr >= n) continue;
        float acc = blin[c];
#pragma unroll
        for (int k = 0; k < CDIM; ++k) acc = fmaf(hs[r * CDIM + k], wl[k * CDIM + c], acc);
        lin_out[(size_t)gr * CDIM + c] = acc;
    }
}

extern "C" void kernel_launch(void* const* d_in, const int* in_sizes, int n_in,
                              void* d_out, int out_size, void* d_ws, size_t ws_size,
                              hipStream_t stream) {
    const float* x    = (const float*)d_in[0];
    const int*   ei   = (const int*)d_in[1];
    const float* W1   = (const float*)d_in[2];
    const float* b1   = (const float*)d_in[3];
    const float* W2   = (const float*)d_in[4];
    const float* b2   = (const float*)d_in[5];
    const float* Wlin = (const float*)d_in[6];
    const float* blin = (const float*)d_in[7];
    float* out = (float*)d_out;

    const int n = in_sizes[0] / FDIM;
    const int E = in_sizes[1] / 2;
    const int* src = ei;
    const int* dst = ei + E;
    const int nb = (n + NPB - 1) / NPB;
    const int nbq = (n + 3) / 4;  // blocks per quarter-phase (4 waves/block)

    char* ws = (char*)d_ws;
    size_t off = 0;
    int*       bcnt  = (int*)(ws + off);       off = AL512(off + (size_t)nb * 4);
    int*       bbase = (int*)(ws + off);       off = AL512(off + (size_t)(nb + 1) * 4);
    int*       bcur  = (int*)(ws + off);       off = AL512(off + (size_t)nb * 4);
    unsigned*  eb    = (unsigned*)(ws + off);  off = AL512(off + (size_t)E * 4);
    int*       offs  = (int*)(ws + off);       off = AL512(off + (size_t)n * 4);
    u16*       ss    = (u16*)(ws + off);       off = AL512(off + (size_t)E * 2);
    float*     dinv  = (float*)(ws + off);     off = AL512(off + (size_t)n * 4);
    _Float16*  W1t   = (_Float16*)(ws + off);  off = AL512(off + (size_t)128 * 128 * 2);
    _Float16*  W2t   = (_Float16*)(ws + off);  off = AL512(off + (size_t)48 * 128 * 2);
    _Float16*  hp1   = (_Float16*)(ws + off);  off = AL512(off + (size_t)n * 128 * 2); // 4 quarters
    _Float16*  h1h   = (_Float16*)(ws + off);  off = AL512(off + (size_t)n * 128 * 2); // 4 quarters
    _Float16*  hp2a  = (_Float16*)(ws + off);  off = AL512(off + (size_t)n * 32 * 2);
    _Float16*  hp2b  = (_Float16*)(ws + off);  off = AL512(off + (size_t)n * 8 * 2);
    (void)ws_size; (void)n_in; (void)out_size;

    float* h2_out  = out;
    float* lin_out = out + (size_t)n * CDIM;

    // weight prep + bcnt zero, then CSR build
    k_prep<<<(128 * 128 + 48 * 128 + 255) / 256, 256, 0, stream>>>(W1, W2, W1t, W2t, bcnt, nb);
    k_bhist<<<256, 256, 0, stream>>>(dst, bcnt, E, nb);
    k_bscan<<<1, 1024, 0, stream>>>(bcnt, bbase, bcur, nb, E);
    k_partition<<<(E + CH - 1) / CH, 256, 0, stream>>>(src, dst, bcur, eb, E, nb);
    k_bucket_csr<<<nb, 256, 0, stream>>>(eb, bbase, offs, dinv, ss, n);

    // conv1
    k_gemm1<<<(n + 63) / 64, 256, 0, stream>>>(x, W1t, dinv, hp1, n);
    k_agg128<<<4 * nbq, 256, 0, stream>>>(ss, offs, hp1, b1, dinv, h1h, n, E, nbq);

    // conv2
    k_gemm2<<<(n + 63) / 64, 256, 0, stream>>>(h1h, W2t, dinv, hp2a, hp2b, n);
    k_agg40<<<2 * nbq, 256, 0, stream>>>(ss, offs, hp2a, hp2b, b2, dinv, h2_out, n, E, nbq);

    // linear head
    k_final<<<(n + 31) / 32, 256, 0, stream>>>(h2_out, Wlin, blin, lin_out, n);
}

// Round 11
// 143.358 us; speedup vs baseline: 1.4248x; 1.4248x over previous
//
#include <hip/hip_runtime.h>

// GCN2: h1 = relu(gcn(x,W1,b1)); h2 = relu(gcn(h1,W2,b2)); out = h2@Wlin+blin
// dinv[s] folded into fp16 h'. CSR via bucket sort (dst>>6) with block-local
// contiguous write runs; ss stored as u16 (n<65536). Dense GEMMs on
// v_mfma_f32_16x16x32_f16 (fp32 accum). Aggregation: one wave per node,
// 16B/lane gathers (4 or 8 neighbor rows per load instruction), shfl_xor
// fold, dinv+bias+relu fused. Round-10 quarter-split reverted (4x wave
// overhead beat the L2-residency gain).

constexpr int FDIM = 128;
constexpr int CDIM = 40;
constexpr int NPB  = 64;    // nodes per bucket
constexpr int MAXNB = 1024; // max buckets
constexpr int CH   = 4096;  // edges per partition block

typedef _Float16 h8  __attribute__((ext_vector_type(8)));
typedef _Float16 h4  __attribute__((ext_vector_type(4)));
typedef float    f4  __attribute__((ext_vector_type(4)));
typedef unsigned short u16;

static inline size_t AL512(size_t x) { return (x + 511) & ~size_t(511); }

// --- weight prep + zero bcnt (replaces hipMemsetAsync) ---
__global__ __launch_bounds__(256) void k_prep(const float* __restrict__ W1,
        const float* __restrict__ W2, _Float16* __restrict__ W1t,
        _Float16* __restrict__ W2t, int* __restrict__ bcnt, int nb) {
    int i = blockIdx.x * 256 + threadIdx.x;
    if (i < nb) bcnt[i] = 0;
    if (i < 128 * 128) {
        int c = i >> 7, k = i & 127;
        W1t[c * 128 + k] = (_Float16)W1[k * 128 + c];
    }
    int j = i - 128 * 128;
    if (j >= 0 && j < 64 * 128) {
        int c = j >> 7, k = j & 127;
        W2t[c * 128 + k] = (c < CDIM) ? (_Float16)W2[k * CDIM + c] : (_Float16)0.f;
    }
}

// --- bucket histogram of dst>>6 ---
__global__ __launch_bounds__(256) void k_bhist(const int* __restrict__ dst,
        int* __restrict__ bcnt, int E, int nb) {
    __shared__ int h[MAXNB];
    for (int i = threadIdx.x; i < nb; i += 256) h[i] = 0;
    __syncthreads();
    for (int i = blockIdx.x * 256 + threadIdx.x; i < E; i += gridDim.x * 256)
        atomicAdd(&h[dst[i] >> 6], 1);
    __syncthreads();
    for (int i = threadIdx.x; i < nb; i += 256) {
        int c = h[i];
        if (c) atomicAdd(&bcnt[i], c);
    }
}

// --- single-block scan over nb bucket counts -> bbase, bcur ---
__global__ __launch_bounds__(1024) void k_bscan(const int* __restrict__ bcnt,
        int* __restrict__ bbase, int* __restrict__ bcur, int nb, int E) {
    __shared__ int tmp[1024];
    int t = threadIdx.x;
    int v = (t < nb) ? bcnt[t] : 0;
    tmp[t] = v;
    __syncthreads();
    for (int o = 1; o < 1024; o <<= 1) {
        int u = (t >= o) ? tmp[t - o] : 0;
        __syncthreads();
        tmp[t] += u;
        __syncthreads();
    }
    if (t < nb) { int b = tmp[t] - v; bbase[t] = b; bcur[t] = b; }
    if (t == 0) bbase[nb] = E;
}

// --- chunked counting sort into bucket runs, packed (src<<6)|(dst&63) ---
__global__ __launch_bounds__(256) void k_partition(const int* __restrict__ src,
        const int* __restrict__ dst, int* __restrict__ bcur,
        unsigned* __restrict__ eb, int E, int nb) {
    __shared__ int hcnt[MAXNB];
    __shared__ int gb[MAXNB];
    int e0 = blockIdx.x * CH;
    int cnt = min(CH, E - e0);
    for (int i = threadIdx.x; i < nb; i += 256) hcnt[i] = 0;
    __syncthreads();
    for (int i = threadIdx.x; i < cnt; i += 256)
        atomicAdd(&hcnt[dst[e0 + i] >> 6], 1);
    __syncthreads();
    for (int i = threadIdx.x; i < nb; i += 256) {
        int c = hcnt[i];
        if (c) gb[i] = atomicAdd(&bcur[i], c);
        hcnt[i] = 0;  // reuse as local cursor
    }
    __syncthreads();
    for (int i = threadIdx.x; i < cnt; i += 256) {
        int d = dst[e0 + i], b = d >> 6;
        int p = atomicAdd(&hcnt[b], 1);
        eb[gb[b] + p] = ((unsigned)src[e0 + i] << 6) | (unsigned)(d & 63);
    }
}

// --- per-bucket counting sort -> per-node CSR (offs, ss u16) + dinv ---
__global__ __launch_bounds__(256) void k_bucket_csr(const unsigned* __restrict__ eb,
        const int* __restrict__ bbase, int* __restrict__ offs,
        float* __restrict__ dinv, u16* __restrict__ ss, int n) {
    __shared__ int cnt[NPB];
    __shared__ int cur[NPB];
    int b = blockIdx.x;
    int beg = bbase[b], end = bbase[b + 1];
    if (threadIdx.x < NPB) cnt[threadIdx.x] = 0;
    __syncthreads();
    for (int i = beg + threadIdx.x; i < end; i += 256)
        atomicAdd(&cnt[eb[i] & 63], 1);
    __syncthreads();
    if (threadIdx.x < NPB) {  // wave 0: 64-lane inclusive shfl scan
        int v = cnt[threadIdx.x];
        int s = v;
#pragma unroll
        for (int o = 1; o < NPB; o <<= 1) {
            int u = __shfl_up(s, o, 64);
            if (threadIdx.x >= (unsigned)o) s += u;
        }
        int e0 = beg + s - v;
        cur[threadIdx.x] = e0;
        int node = b * NPB + threadIdx.x;
        if (node < n) {
            offs[node] = e0;
            dinv[node] = rsqrtf((float)v + 1.0f);  // +1 self loop
        }
    }
    __syncthreads();
    for (int i = beg + threadIdx.x; i < end; i += 256) {
        unsigned p = eb[i];
        int pos = atomicAdd(&cur[p & 63], 1);
        ss[pos] = (u16)(p >> 6);
    }
}

// Hp[r][c] = fp16( (X[r] @ W1)[c] * dinv[r] )  -- MFMA 16x16x32 f16
__global__ __launch_bounds__(256) void k_gemm1(const float* __restrict__ X,
        const _Float16* __restrict__ W1t, const float* __restrict__ dinv,
        _Float16* __restrict__ Hp, int n) {
    __shared__ _Float16 xh[64][136];   // +8 pad: 2-way LDS conflict (free)
    __shared__ _Float16 wt[128][136];
    int t = threadIdx.x;
    int r0 = blockIdx.x * 64;
    for (int i = t; i < 64 * 32; i += 256) {
        int r = i >> 5, c4 = (i & 31) * 4;
        int gr = r0 + r;
        float4 v = make_float4(0.f, 0.f, 0.f, 0.f);
        if (gr < n) v = *(const float4*)&X[(size_t)gr * 128 + c4];
        h4 hv; hv[0] = (_Float16)v.x; hv[1] = (_Float16)v.y;
               hv[2] = (_Float16)v.z; hv[3] = (_Float16)v.w;
        *(h4*)&xh[r][c4] = hv;
    }
    for (int i = t; i < 128 * 16; i += 256) {
        int r = i >> 4, c8 = (i & 15) * 8;
        *(uint4*)&wt[r][c8] = *(const uint4*)&W1t[r * 128 + c8];
    }
    __syncthreads();
    int wid = t >> 6, lane = t & 63;
    int fr = lane & 15, fg = lane >> 4;
    f4 acc[8];
#pragma unroll
    for (int ct = 0; ct < 8; ++ct) acc[ct] = (f4){0.f, 0.f, 0.f, 0.f};
#pragma unroll
    for (int ks = 0; ks < 4; ++ks) {
        h8 a = *(const h8*)&xh[wid * 16 + fr][ks * 32 + fg * 8];
#pragma unroll
        for (int ct = 0; ct < 8; ++ct) {
            h8 b = *(const h8*)&wt[ct * 16 + fr][ks * 32 + fg * 8];
            acc[ct] = __builtin_amdgcn_mfma_f32_16x16x32_f16(a, b, acc[ct], 0, 0, 0);
        }
    }
    int rbase = r0 + wid * 16 + fg * 4;  // C/D: row=(lane>>4)*4+reg, col=lane&15
    float dv[4];
#pragma unroll
    for (int rg = 0; rg < 4; ++rg) dv[rg] = (rbase + rg < n) ? dinv[rbase + rg] : 0.f;
#pragma unroll
    for (int ct = 0; ct < 8; ++ct)
#pragma unroll
        for (int rg = 0; rg < 4; ++rg) {
            int gr = rbase + rg;
            if (gr < n) Hp[(size_t)gr * 128 + ct * 16 + fr] = (_Float16)(acc[ct][rg] * dv[rg]);
        }
}

// h1[d] = fp16(relu(dinv[d]*(hp[d]+sum hp[s]) + b1))
// 16B/lane: 4 neighbor rows per load; up to 4 loads in flight.
__global__ __launch_bounds__(256) void k_agg128(const u16* __restrict__ ss,
        const int* __restrict__ offs, const _Float16* __restrict__ hp,
        const float* __restrict__ b1, const float* __restrict__ dinv,
        _Float16* __restrict__ h1, int n, int E) {
    int w = (blockIdx.x * 256 + threadIdx.x) >> 6;
    int lane = threadIdx.x & 63;
    if (w >= n) return;
    int beg = offs[w];
    int end = (w == n - 1) ? E : offs[w + 1];
    const h8* hpv = (const h8*)hp;
    int g = lane >> 4, c = lane & 15;
    h8 sv = hpv[(size_t)w * 16 + c];  // self row
    float acc[8];
#pragma unroll
    for (int i = 0; i < 8; ++i) acc[i] = (g == 0) ? (float)sv[i] : 0.f;
    int j = beg;
    for (; j + 15 < end; j += 16) {  // 16 edges/iter, 4 loads in flight
        int s0 = ss[j + g];
        int s1 = ss[j + 4 + g];
        int s2 = ss[j + 8 + g];
        int s3 = ss[j + 12 + g];
        h8 v0 = hpv[(size_t)s0 * 16 + c];
        h8 v1 = hpv[(size_t)s1 * 16 + c];
        h8 v2 = hpv[(size_t)s2 * 16 + c];
        h8 v3 = hpv[(size_t)s3 * 16 + c];
#pragma unroll
        for (int i = 0; i < 8; ++i)
            acc[i] += ((float)v0[i] + (float)v1[i]) + ((float)v2[i] + (float)v3[i]);
    }
    for (; j + 7 < end; j += 8) {
        int s0 = ss[j + g];
        int s1 = ss[j + 4 + g];
        h8 v0 = hpv[(size_t)s0 * 16 + c];
        h8 v1 = hpv[(size_t)s1 * 16 + c];
#pragma unroll
        for (int i = 0; i < 8; ++i) acc[i] += (float)v0[i] + (float)v1[i];
    }
    for (; j < end; j += 4) {
        int idx = j + g;
        if (idx < end) {
            int s = ss[idx];
            h8 v = hpv[(size_t)s * 16 + c];
#pragma unroll
            for (int i = 0; i < 8; ++i) acc[i] += (float)v[i];
        }
    }
#pragma unroll
    for (int i = 0; i < 8; ++i) {  // fold 4 group-partials
        acc[i] += __shfl_xor(acc[i], 16);
        acc[i] += __shfl_xor(acc[i], 32);
    }
    if (lane < 16) {  // lane l holds cols 8l..8l+7
        float dvv = dinv[w];
        const float4 bb0 = *(const float4*)&b1[8 * lane];
        const float4 bb1 = *(const float4*)&b1[8 * lane + 4];
        h8 o;
        o[0] = (_Float16)fmaxf(fmaf(dvv, acc[0], bb0.x), 0.f);
        o[1] = (_Float16)fmaxf(fmaf(dvv, acc[1], bb0.y), 0.f);
        o[2] = (_Float16)fmaxf(fmaf(dvv, acc[2], bb0.z), 0.f);
        o[3] = (_Float16)fmaxf(fmaf(dvv, acc[3], bb0.w), 0.f);
        o[4] = (_Float16)fmaxf(fmaf(dvv, acc[4], bb1.x), 0.f);
        o[5] = (_Float16)fmaxf(fmaf(dvv, acc[5], bb1.y), 0.f);
        o[6] = (_Float16)fmaxf(fmaf(dvv, acc[6], bb1.z), 0.f);
        o[7] = (_Float16)fmaxf(fmaf(dvv, acc[7], bb1.w), 0.f);
        *(h8*)&h1[(size_t)w * 128 + 8 * lane] = o;
    }
}

// Hp2[r][c] = fp16( (h1[r] @ W2)[c] * dinv[r] ), 64-col padded (cols>=40 = 0)
__global__ __launch_bounds__(256) void k_gemm2(const _Float16* __restrict__ H1,
        const _Float16* __restrict__ W2t, const float* __restrict__ dinv,
        _Float16* __restrict__ Hp2, int n) {
    __shared__ _Float16 xh[64][136];
    __shared__ _Float16 wt[64][136];
    int t = threadIdx.x;
    int r0 = blockIdx.x * 64;
    for (int i = t; i < 64 * 16; i += 256) {
        int r = i >> 4, c8 = (i & 15) * 8;
        int gr = r0 + r;
        uint4 v = make_uint4(0u, 0u, 0u, 0u);
        if (gr < n) v = *(const uint4*)&H1[(size_t)gr * 128 + c8];
        *(uint4*)&xh[r][c8] = v;
    }
    for (int i = t; i < 64 * 16; i += 256) {
        int r = i >> 4, c8 = (i & 15) * 8;
        *(uint4*)&wt[r][c8] = *(const uint4*)&W2t[r * 128 + c8];
    }
    __syncthreads();
    int wid = t >> 6, lane = t & 63;
    int fr = lane & 15, fg = lane >> 4;
    f4 acc[4];
#pragma unroll
    for (int ct = 0; ct < 4; ++ct) acc[ct] = (f4){0.f, 0.f, 0.f, 0.f};
#pragma unroll
    for (int ks = 0; ks < 4; ++ks) {
        h8 a = *(const h8*)&xh[wid * 16 + fr][ks * 32 + fg * 8];
#pragma unroll
        for (int ct = 0; ct < 4; ++ct) {
            h8 b = *(const h8*)&wt[ct * 16 + fr][ks * 32 + fg * 8];
            acc[ct] = __builtin_amdgcn_mfma_f32_16x16x32_f16(a, b, acc[ct], 0, 0, 0);
        }
    }
    int rbase = r0 + wid * 16 + fg * 4;
    float dv[4];
#pragma unroll
    for (int rg = 0; rg < 4; ++rg) dv[rg] = (rbase + rg < n) ? dinv[rbase + rg] : 0.f;
#pragma unroll
    for (int ct = 0; ct < 4; ++ct)
#pragma unroll
        for (int rg = 0; rg < 4; ++rg) {
            int gr = rbase + rg;
            if (gr < n) Hp2[(size_t)gr * 64 + ct * 16 + fr] = (_Float16)(acc[ct][rg] * dv[rg]);
        }
}

// h2[d] = relu(dinv[d]*(hp2[d]+sum hp2[s]) + b2) -> d_out (40 fp32/row)
// hp2 rows are 64 fp16 (128B); 16B/lane -> 8 rows per load instruction.
__global__ __launch_bounds__(256) void k_agg40(const u16* __restrict__ ss,
        const int* __restrict__ offs, const _Float16* __restrict__ hp,
        const float* __restrict__ b2, const float* __restrict__ dinv,
        float* __restrict__ h2out, int n, int E) {
    int w = (blockIdx.x * 256 + threadIdx.x) >> 6;
    int lane = threadIdx.x & 63;
    if (w >= n) return;
    int beg = offs[w];
    int end = (w == n - 1) ? E : offs[w + 1];
    const h8* hpv = (const h8*)hp;
    int g = lane >> 3, c = lane & 7;
    h8 sv = hpv[(size_t)w * 8 + c];  // self row
    float acc[8];
#pragma unroll
    for (int i = 0; i < 8; ++i) acc[i] = (g == 0) ? (float)sv[i] : 0.f;
    int j = beg;
    for (; j + 15 < end; j += 16) {  // 16 edges/iter, 2 loads in flight
        int s0 = ss[j + g];
        int s1 = ss[j + 8 + g];
        h8 v0 = hpv[(size_t)s0 * 8 + c];
        h8 v1 = hpv[(size_t)s1 * 8 + c];
#pragma unroll
        for (int i = 0; i < 8; ++i) acc[i] += (float)v0[i] + (float)v1[i];
    }
    for (; j < end; j += 8) {
        int idx = j + g;
        if (idx < end) {
            int s = ss[idx];
            h8 v = hpv[(size_t)s * 8 + c];
#pragma unroll
            for (int i = 0; i < 8; ++i) acc[i] += (float)v[i];
        }
    }
#pragma unroll
    for (int i = 0; i < 8; ++i) {  // fold 8 group-partials
        acc[i] += __shfl_xor(acc[i], 8);
        acc[i] += __shfl_xor(acc[i], 16);
        acc[i] += __shfl_xor(acc[i], 32);
    }
    if (lane < 5) {  // lane l holds cols 8l..8l+7; cols 40..63 are padding
        float dvv = dinv[w];
        const float4 bb0 = *(const float4*)&b2[8 * lane];
        const float4 bb1 = *(const float4*)&b2[8 * lane + 4];
        float4 r0, r1;
        r0.x = fmaxf(fmaf(dvv, acc[0], bb0.x), 0.f);
        r0.y = fmaxf(fmaf(dvv, acc[1], bb0.y), 0.f);
        r0.z = fmaxf(fmaf(dvv, acc[2], bb0.z), 0.f);
        r0.w = fmaxf(fmaf(dvv, acc[3], bb0.w), 0.f);
        r1.x = fmaxf(fmaf(dvv, acc[4], bb1.x), 0.f);
        r1.y = fmaxf(fmaf(dvv, acc[5], bb1.y), 0.f);
        r1.z = fmaxf(fmaf(dvv, acc[6], bb1.z), 0.f);
        r1.w = fmaxf(fmaf(dvv, acc[7], bb1.w), 0.f);
        *(float4*)&h2out[(size_t)w * CDIM + 8 * lane] = r0;
        *(float4*)&h2out[(size_t)w * CDIM + 8 * lane + 4] = r1;
    }
}

// lin_out = h2 @ Wlin + blin  (h2 read back from d_out)
__global__ __launch_bounds__(256) void k_final(const float* __restrict__ h2,
        const float* __restrict__ Wlin, const float* __restrict__ blin,
        float* __restrict__ lin_out, int n) {
    __shared__ float wl[CDIM * CDIM];
    __shared__ float hs[32 * CDIM];
    int t = threadIdx.x;
    int r0 = blockIdx.x * 32;
    for (int i = t; i < CDIM * CDIM; i += 256) wl[i] = Wlin[i];
    int lim = n * CDIM - r0 * CDIM;
    for (int i = t; i < 32 * CDIM; i += 256)
        hs[i] = (i < lim) ? h2[(size_t)r0 * CDIM + i] : 0.f;
    __syncthreads();
    for (int i = t; i < 32 * CDIM; i += 256) {
        int r = i / CDIM, c = i % CDIM;
        int gr = r0 + r;
        if (gr >= n) continue;
        float acc = blin[c];
#pragma unroll
        for (int k = 0; k < CDIM; ++k) acc = fmaf(hs[r * CDIM + k], wl[k * CDIM + c], acc);
        lin_out[(size_t)gr * CDIM + c] = acc;
    }
}

extern "C" void kernel_launch(void* const* d_in, const int* in_sizes, int n_in,
                              void* d_out, int out_size, void* d_ws, size_t ws_size,
                              hipStream_t stream) {
    const float* x    = (const float*)d_in[0];
    const int*   ei   = (const int*)d_in[1];
    const float* W1   = (const float*)d_in[2];
    const float* b1   = (const float*)d_in[3];
    const float* W2   = (const float*)d_in[4];
    const float* b2   = (const float*)d_in[5];
    const float* Wlin = (const float*)d_in[6];
    const float* blin = (const float*)d_in[7];
    float* out = (float*)d_out;

    const int n = in_sizes[0] / FDIM;
    const int E = in_sizes[1] / 2;
    const int* src = ei;
    const int* dst = ei + E;
    const int nb = (n + NPB - 1) / NPB;

    char* ws = (char*)d_ws;
    size_t off = 0;
    int*       bcnt  = (int*)(ws + off);       off = AL512(off + (size_t)nb * 4);
    int*       bbase = (int*)(ws + off);       off = AL512(off + (size_t)(nb + 1) * 4);
    int*       bcur  = (int*)(ws + off);       off = AL512(off + (size_t)nb * 4);
    unsigned*  eb    = (unsigned*)(ws + off);  off = AL512(off + (size_t)E * 4);
    int*       offs  = (int*)(ws + off);       off = AL512(off + (size_t)n * 4);
    u16*       ss    = (u16*)(ws + off);       off = AL512(off + (size_t)E * 2);
    float*     dinv  = (float*)(ws + off);     off = AL512(off + (size_t)n * 4);
    _Float16*  W1t   = (_Float16*)(ws + off);  off = AL512(off + (size_t)128 * 128 * 2);
    _Float16*  W2t   = (_Float16*)(ws + off);  off = AL512(off + (size_t)64 * 128 * 2);
    _Float16*  hp1   = (_Float16*)(ws + off);  off = AL512(off + (size_t)n * FDIM * 2);
    _Float16*  h1h   = (_Float16*)(ws + off);  off = AL512(off + (size_t)n * FDIM * 2);
    _Float16*  hp2   = (_Float16*)(ws + off);  off = AL512(off + (size_t)n * 64 * 2);
    (void)ws_size; (void)n_in; (void)out_size;

    float* h2_out  = out;
    float* lin_out = out + (size_t)n * CDIM;

    // weight prep + bcnt zero, then CSR build
    k_prep<<<(128 * 128 + 64 * 128 + 255) / 256, 256, 0, stream>>>(W1, W2, W1t, W2t, bcnt, nb);
    k_bhist<<<256, 256, 0, stream>>>(dst, bcnt, E, nb);
    k_bscan<<<1, 1024, 0, stream>>>(bcnt, bbase, bcur, nb, E);
    k_partition<<<(E + CH - 1) / CH, 256, 0, stream>>>(src, dst, bcur, eb, E, nb);
    k_bucket_csr<<<nb, 256, 0, stream>>>(eb, bbase, offs, dinv, ss, n);

    // conv1
    k_gemm1<<<(n + 63) / 64, 256, 0, stream>>>(x, W1t, dinv, hp1, n);
    k_agg128<<<(n * 64 + 255) / 256, 256, 0, stream>>>(ss, offs, hp1, b1, dinv, h1h, n, E);

    // conv2
    k_gemm2<<<(n + 63) / 64, 256, 0, stream>>>(h1h, W2t, dinv, hp2, n);
    k_agg40<<<(n * 64 + 255) / 256, 256, 0, stream>>>(ss, offs, hp2, b2, dinv, h2_out, n, E);

    // linear head
    k_final<<<(n + 31) / 32, 256, 0, stream>>>(h2_out, Wlin, blin, lin_out, n);
}